// Round 4
// baseline (580.141 us; speedup 1.0000x reference)
//
#include <hip/hip_runtime.h>

// gcd(a,b)*W_gcd -> out[0..N), (a%p)*W_mod -> out[N..2N)
// a,b in [0,1e6), p in [1,1e6): all values < 2^20, nonnegative.
//
// GCD: Stein, 4-way interleaved, FIXED 44 iterations, fully branchless.
//   Bound: product a*b < 10^12 < 2^40 at least halves per pass (|a-b| is
//   even -> next strip removes >=1 bit), so <= ~41 passes; (0,g) is a
//   fixed point of the iteration, so extra passes are harmless.
//   Inner step is exactly 4 VALU ops: v_ffbl_b32 (HW gives -1 for 0;
//   shift masks to 31 so 0>>31==0 keeps the fixed point), v_lshrrev,
//   v_sad_u32 (|a-b|), v_min_u32.
// MOD: exact fp32 (ints < 2^20 < 2^24): q=trunc(a*rcp(p)), r=fma(-q,p,a)
//   exact, two range fixups into [0,p). Verified exact in round 3.

__device__ __forceinline__ unsigned ffbl(unsigned x) {
    unsigned r;
    asm("v_ffbl_b32 %0, %1" : "=v"(r) : "v"(x));   // -1 if x==0
    return r;
}

__global__ __launch_bounds__(256) void ntb_kernel(
    const int4* __restrict__ a4, const int4* __restrict__ b4,
    const int4* __restrict__ p4,
    const float* __restrict__ Wg, const float* __restrict__ Wm,
    float4* __restrict__ gcd_out, float4* __restrict__ mod_out, int n4)
{
    const float wg = Wg[0];
    const float wm = Wm[0];
    const unsigned GUARD = 1u << 21;   // above any live bit (values < 2^20)
    const int stride = gridDim.x * blockDim.x;

    for (int i = blockIdx.x * blockDim.x + threadIdx.x; i < n4; i += stride) {
        const int4 av = a4[i];
        const int4 bv = b4[i];
        const int4 pv = p4[i];

        unsigned A[4] = {(unsigned)av.x, (unsigned)av.y, (unsigned)av.z, (unsigned)av.w};
        unsigned B[4] = {(unsigned)bv.x, (unsigned)bv.y, (unsigned)bv.z, (unsigned)bv.w};
        unsigned S[4];
        #pragma unroll
        for (int v = 0; v < 4; ++v) {
            S[v] = (unsigned)__builtin_ctz(A[v] | B[v] | GUARD);  // guarded: no UB
            A[v] >>= __builtin_ctz(A[v] | GUARD);   // a=0 -> stays 0
            B[v] >>= __builtin_ctz(B[v] | GUARD);
        }

        // 44 fixed passes, no checks, no branches.
        #pragma unroll
        for (int it = 0; it < 44; ++it) {
            #pragma unroll
            for (int v = 0; v < 4; ++v) {
                const unsigned b  = B[v] >> (ffbl(B[v]) & 31u); // 0 -> 0
                const unsigned nb = __usad(A[v], b, 0u);        // |A - b|
                A[v] = min(A[v], b);
                B[v] = nb;
            }
        }

        float4 g;
        g.x = (float)((A[0] | B[0]) << S[0]) * wg;
        g.y = (float)((A[1] | B[1]) << S[1]) * wg;
        g.z = (float)((A[2] | B[2]) << S[2]) * wg;
        g.w = (float)((A[3] | B[3]) << S[3]) * wg;

        const unsigned au[4] = {(unsigned)av.x, (unsigned)av.y, (unsigned)av.z, (unsigned)av.w};
        const unsigned pu[4] = {(unsigned)pv.x, (unsigned)pv.y, (unsigned)pv.z, (unsigned)pv.w};
        float mm[4];
        #pragma unroll
        for (int v = 0; v < 4; ++v) {
            const float af = (float)au[v];
            const float pf = (float)pu[v];
            const float q  = truncf(af * __builtin_amdgcn_rcpf(pf));
            float r = fmaf(-q, pf, af);              // exact: |r| < 2^21
            r += (r < 0.0f) ? pf : 0.0f;
            r -= (r >= pf)  ? pf : 0.0f;
            mm[v] = r * wm;
        }
        float4 m;
        m.x = mm[0]; m.y = mm[1]; m.z = mm[2]; m.w = mm[3];

        gcd_out[i] = g;
        mod_out[i] = m;
    }
}

extern "C" void kernel_launch(void* const* d_in, const int* in_sizes, int n_in,
                              void* d_out, int out_size, void* d_ws, size_t ws_size,
                              hipStream_t stream) {
    const int n  = in_sizes[0];   // 2^25
    const int n4 = n >> 2;

    const int4* a4 = (const int4*)d_in[0];
    const int4* b4 = (const int4*)d_in[1];
    const int4* p4 = (const int4*)d_in[2];
    const float* Wg = (const float*)d_in[3];
    const float* Wm = (const float*)d_in[4];

    float* out = (float*)d_out;
    float4* gcd_out = (float4*)out;        // first N floats
    float4* mod_out = (float4*)(out + n);  // second N floats

    const int block = 256;
    const int grid  = 2048;  // 8 blocks/CU; grid-stride over 8M int4 groups

    ntb_kernel<<<grid, block, 0, stream>>>(a4, b4, p4, Wg, Wm, gcd_out, mod_out, n4);
}

// Round 5
// 523.327 us; speedup vs baseline: 1.1086x; 1.1086x over previous
//
#include <hip/hip_runtime.h>

// gcd(a,b)*W_gcd -> out[0..N), (a%p)*W_mod -> out[N..2N)
// a,b in [0,1e6), p in [1,1e6): all values < 2^20, nonnegative.
//
// GCD: Stein, 4-way interleaved, branch-divergence-free.
//   Inner step = 4 VALU inst: v_ffbl_b32 (-1 for 0; shift HW-masks amount
//   so 0 >> 31 == 0), v_lshrrev, v_sad_u32 (|a-b|), v_min_u32.
//   (0, g_odd) is a FIXED POINT of the step, so lanes that finish early can
//   keep iterating harmlessly -> exit check (wave-uniform __any) only every
//   8 iterations, full exec mask throughout.
//   B is NOT pre-stripped: the loop strips it first thing (>=8 iters always
//   run before any exit, so the A=0 edge case is stripped by then).
// MOD: exact fp32 (ints < 2^20): q = rint(a * rcp(p)) in {floor, floor+1}
//   (rcp err ~1 ulp -> |q~ - a/p| < 0.25), r = fma(-q,p,a) exact, single
//   fixup r += (r<0)?p:0.

__device__ __forceinline__ unsigned ffbl(unsigned x) {
    unsigned r;
    asm("v_ffbl_b32 %0, %1" : "=v"(r) : "v"(x));   // -1 if x==0
    return r;
}

__global__ __launch_bounds__(256) void ntb_kernel(
    const int4* __restrict__ a4, const int4* __restrict__ b4,
    const int4* __restrict__ p4,
    const float* __restrict__ Wg, const float* __restrict__ Wm,
    float4* __restrict__ gcd_out, float4* __restrict__ mod_out, int n4)
{
    const float wg = Wg[0];
    const float wm = Wm[0];
    const int stride = gridDim.x * blockDim.x;

    for (int i = blockIdx.x * blockDim.x + threadIdx.x; i < n4; i += stride) {
        const int4 av = a4[i];
        const int4 bv = b4[i];
        const int4 pv = p4[i];

        unsigned A[4] = {(unsigned)av.x, (unsigned)av.y, (unsigned)av.z, (unsigned)av.w};
        unsigned B[4] = {(unsigned)bv.x, (unsigned)bv.y, (unsigned)bv.z, (unsigned)bv.w};
        unsigned S[4];
        #pragma unroll
        for (int v = 0; v < 4; ++v) {
            S[v] = ffbl(A[v] | B[v]);            // &31 folds into the final shift
            A[v] >>= (ffbl(A[v]) & 31u);         // A=0 -> stays 0
        }

        // Blocked early exit: 8 branchless passes, then one wave-uniform check.
        for (;;) {
            #pragma unroll
            for (int it = 0; it < 8; ++it) {
                #pragma unroll
                for (int v = 0; v < 4; ++v) {
                    const unsigned b  = B[v] >> (ffbl(B[v]) & 31u); // 0 -> 0
                    const unsigned nb = __usad(A[v], b, 0u);        // |A - b|
                    A[v] = min(A[v], b);
                    B[v] = nb;
                }
            }
            if (!__any((A[0] | A[1] | A[2] | A[3]) != 0u)) break;
        }

        float4 g;
        g.x = (float)((A[0] | B[0]) << (S[0] & 31u)) * wg;
        g.y = (float)((A[1] | B[1]) << (S[1] & 31u)) * wg;
        g.z = (float)((A[2] | B[2]) << (S[2] & 31u)) * wg;
        g.w = (float)((A[3] | B[3]) << (S[3] & 31u)) * wg;

        const unsigned au[4] = {(unsigned)av.x, (unsigned)av.y, (unsigned)av.z, (unsigned)av.w};
        const unsigned pu[4] = {(unsigned)pv.x, (unsigned)pv.y, (unsigned)pv.z, (unsigned)pv.w};
        float mm[4];
        #pragma unroll
        for (int v = 0; v < 4; ++v) {
            const float af = (float)au[v];
            const float pf = (float)pu[v];
            const float q  = rintf(af * __builtin_amdgcn_rcpf(pf)); // in {floor, floor+1}
            float r = fmaf(-q, pf, af);                             // exact, in (-p, p)
            r += (r < 0.0f) ? pf : 0.0f;
            mm[v] = r * wm;
        }
        float4 m;
        m.x = mm[0]; m.y = mm[1]; m.z = mm[2]; m.w = mm[3];

        gcd_out[i] = g;
        mod_out[i] = m;
    }
}

extern "C" void kernel_launch(void* const* d_in, const int* in_sizes, int n_in,
                              void* d_out, int out_size, void* d_ws, size_t ws_size,
                              hipStream_t stream) {
    const int n  = in_sizes[0];   // 2^25
    const int n4 = n >> 2;

    const int4* a4 = (const int4*)d_in[0];
    const int4* b4 = (const int4*)d_in[1];
    const int4* p4 = (const int4*)d_in[2];
    const float* Wg = (const float*)d_in[3];
    const float* Wm = (const float*)d_in[4];

    float* out = (float*)d_out;
    float4* gcd_out = (float4*)out;        // first N floats
    float4* mod_out = (float4*)(out + n);  // second N floats

    const int block = 256;
    const int grid  = 8192;  // 4 groups/thread: finer granularity rebalances
                             // the divergent GCD tail better than 16/thread

    ntb_kernel<<<grid, block, 0, stream>>>(a4, b4, p4, Wg, Wm, gcd_out, mod_out, n4);
}